// Round 16
// baseline (177.327 us; speedup 1.0000x reference)
//
#include <hip/hip_runtime.h>
#include <stdint.h>

// ContrastiveLoss: B=8192, D=1024, n=2048, T=0.5
// K1: row-normalize f32 -> fp8 e4m3, PRE-SWIZZLED row-major layout
//     (16B chunk c of row r stored at position c^(r&7) within its 128B window)
// K2: 128x256-tile MX-fp8 GEMM, 512 thr (8 waves 2x4, wave=64x64, acc=64),
//     T14 async-STAGE: global->reg prefetch of tile t+1 issued BEFORE compute(t),
//     ds_write after barrier. Single 48KB LDS. (512,4) = 128 regs, 2 blocks/CU.
// K3: scalar finalize

#define BDIM 1024
#define BROWS 8192
#define NROWS 2048

#define BM 128
#define BN 256
#define BKB 128            // fp8 K-bytes per tile
#define NKT (BDIM / BKB)   // 8

typedef __attribute__((ext_vector_type(4))) int i32x4;
typedef __attribute__((ext_vector_type(8))) int i32x8;
typedef __attribute__((ext_vector_type(4))) float f32x4;

// float -> OCP e4m3fn, RNE, handles subnormals (|x| <= 1 for our data)
static __device__ __forceinline__ unsigned char f2e4m3(float x) {
  uint32_t u = __float_as_uint(x);
  uint32_t s = (u >> 24) & 0x80u;
  uint32_t a = u & 0x7fffffffu;
  if (a == 0) return (unsigned char)s;
  int e = (int)(a >> 23) - 127;
  uint32_t m = a & 0x7fffffu;
  if (e >= -6) {
    uint32_t keep = m >> 20;
    uint32_t rest = m & 0xfffffu;
    keep += (rest > 0x80000u) || (rest == 0x80000u && (keep & 1u));
    uint32_t v = ((uint32_t)(e + 7) << 3) + keep;
    return (unsigned char)(s | v);
  }
  if (e < -10) return (unsigned char)s;
  uint32_t full = 0x800000u | m;
  int sh = 14 - e;
  uint32_t keep = full >> sh;
  uint32_t rest = full & ((1u << sh) - 1u);
  uint32_t half = 1u << (sh - 1);
  keep += (rest > half) || (rest == half && (keep & 1u));
  return (unsigned char)(s | keep);
}

static __device__ __forceinline__ uint32_t pk4(float4 v, float inv) {
  return (uint32_t)f2e4m3(v.x * inv) | ((uint32_t)f2e4m3(v.y * inv) << 8) |
         ((uint32_t)f2e4m3(v.z * inv) << 16) | ((uint32_t)f2e4m3(v.w * inv) << 24);
}

__global__ __launch_bounds__(256) void normalize_kernel(const float* __restrict__ emb,
                                                        unsigned char* __restrict__ zb,
                                                        float* __restrict__ denom,
                                                        float* __restrict__ sumsim) {
  const int w = threadIdx.x >> 6;
  const int lane = threadIdx.x & 63;
  const int row = blockIdx.x * 4 + w;
  const float4* src = reinterpret_cast<const float4*>(emb + (size_t)row * BDIM);
  float4 v[4];
  float ss = 0.f;
#pragma unroll
  for (int i = 0; i < 4; i++) {
    v[i] = src[lane * 4 + i];
    ss += v[i].x * v[i].x + v[i].y * v[i].y + v[i].z * v[i].z + v[i].w * v[i].w;
  }
#pragma unroll
  for (int m = 1; m < 64; m <<= 1) ss += __shfl_xor(ss, m);
  const float inv = rsqrtf(ss);
  uint4 o;
  o.x = pk4(v[0], inv);
  o.y = pk4(v[1], inv);
  o.z = pk4(v[2], inv);
  o.w = pk4(v[3], inv);
  // pre-swizzle: logical chunk (lane) stored at position (lane&56)|((lane&7)^(row&7))
  const int cp = (lane & 56) | ((lane & 7) ^ (row & 7));
  *reinterpret_cast<uint4*>(zb + (size_t)row * BDIM + cp * 16) = o;
  if (blockIdx.x < NROWS / 4 && lane == 0) denom[row] = 0.f;
  if (blockIdx.x == 0 && threadIdx.x == 0) sumsim[0] = 0.f;
}

// ---------------- GEMM ----------------
// zb PRE-SWIZZLED: position p of row r holds logical chunk p^(r&7).
// Reg-staged copy is position-preserving -> LDS inherits swizzle; frag reads
// apply chunk^(row&7) (proven numerics since R8).
// Per tile: issue 6 global_load_dwordx4 (t+1) -> compute(t) covers latency ->
// barrier -> 6 ds_write_b128 (conflict-free) -> barrier.

__global__ __launch_bounds__(512, 4) void gemm_fused(const unsigned char* __restrict__ zb,
                                                     float* __restrict__ denom,
                                                     float* __restrict__ sumsim) {
  __shared__ unsigned char As[BM * BKB];   // 16 KB
  __shared__ unsigned char Bs[BN * BKB];   // 32 KB

  // XCD-chunked: xcd owns 4 j-blocks x all 16 i-blocks (A 2MB + B 1MB < 4MB L2)
  const int bx = blockIdx.x;            // 0..511
  const int xcd = bx & 7;
  const int idx = bx >> 3;              // 0..63
  const int jb = xcd * 4 + (idx & 3);   // 0..31
  const int ib = idx >> 2;              // 0..15
  const int i0 = ib * BM;               // [0,2048)
  const int j0 = jb * BN;               // [0,8192)

  const int t = threadIdx.x;
  const int lane = t & 63;
  const int w = t >> 6;                 // 0..7
  const int WR = w >> 2;                // 0..1
  const int WC = w & 3;                 // 0..3

  // staging lanes: 8 rows x 128B per unit, linear
  const int rsh = lane >> 3;
  const int lin = (lane & 7) * 16;
  // this wave's 6 staging units: A groups 2w,2w+1 ; B groups 4w..4w+3
  const unsigned char* gA0 = zb + (size_t)(i0 + (2 * w) * 8 + rsh) * BDIM + lin;
  const unsigned char* gA1 = zb + (size_t)(i0 + (2 * w + 1) * 8 + rsh) * BDIM + lin;
  const unsigned char* gB0 = zb + (size_t)(j0 + (4 * w) * 8 + rsh) * BDIM + lin;
  const unsigned char* gB1 = zb + (size_t)(j0 + (4 * w + 1) * 8 + rsh) * BDIM + lin;
  const unsigned char* gB2 = zb + (size_t)(j0 + (4 * w + 2) * 8 + rsh) * BDIM + lin;
  const unsigned char* gB3 = zb + (size_t)(j0 + (4 * w + 3) * 8 + rsh) * BDIM + lin;
  uint4* lA0 = reinterpret_cast<uint4*>(&As[((2 * w) * 8 + rsh) * BKB + lin]);
  uint4* lA1 = reinterpret_cast<uint4*>(&As[((2 * w + 1) * 8 + rsh) * BKB + lin]);
  uint4* lB0 = reinterpret_cast<uint4*>(&Bs[((4 * w) * 8 + rsh) * BKB + lin]);
  uint4* lB1 = reinterpret_cast<uint4*>(&Bs[((4 * w + 1) * 8 + rsh) * BKB + lin]);
  uint4* lB2 = reinterpret_cast<uint4*>(&Bs[((4 * w + 2) * 8 + rsh) * BKB + lin]);
  uint4* lB3 = reinterpret_cast<uint4*>(&Bs[((4 * w + 3) * 8 + rsh) * BKB + lin]);

  // fragment reads
  const int q2 = lane >> 4;             // 0..3 -> k-chunks {2q2, 2q2+1}
  const int rsub = lane & 15;
  const int rk = rsub & 7;

  f32x4 acc[4][4] = {};
  uint4 pA0, pA1, pB0, pB1, pB2, pB3;

#define LOADP(kk)                                                       \
  {                                                                     \
    pA0 = *reinterpret_cast<const uint4*>(gA0 + (kk));                  \
    pA1 = *reinterpret_cast<const uint4*>(gA1 + (kk));                  \
    pB0 = *reinterpret_cast<const uint4*>(gB0 + (kk));                  \
    pB1 = *reinterpret_cast<const uint4*>(gB1 + (kk));                  \
    pB2 = *reinterpret_cast<const uint4*>(gB2 + (kk));                  \
    pB3 = *reinterpret_cast<const uint4*>(gB3 + (kk));                  \
  }
#define WRITEP()                                                        \
  { *lA0 = pA0; *lA1 = pA1; *lB0 = pB0; *lB1 = pB1; *lB2 = pB2; *lB3 = pB3; }

#define RD_FRAG(dst, base, row)                                                                                  \
  {                                                                                                              \
    const i32x4 lo = *reinterpret_cast<const i32x4*>(&base[(size_t)(row) * BKB + (((2 * q2) ^ rk) * 16)]);       \
    const i32x4 hi = *reinterpret_cast<const i32x4*>(&base[(size_t)(row) * BKB + (((2 * q2 + 1) ^ rk) * 16)]);   \
    dst[0] = lo[0]; dst[1] = lo[1]; dst[2] = lo[2]; dst[3] = lo[3];                                              \
    dst[4] = hi[0]; dst[5] = hi[1]; dst[6] = hi[2]; dst[7] = hi[3];                                              \
  }

  // ---- prologue: tile 0 via regs ----
  LOADP(0);
  WRITEP();
  __syncthreads();

#pragma unroll 1
  for (int kt = 0; kt < NKT; ++kt) {
    if (kt + 1 < NKT) LOADP((kt + 1) * BKB);   // issue early: covered by compute

    i32x8 bb[4];
#pragma unroll
    for (int nn = 0; nn < 4; nn++) {
      RD_FRAG(bb[nn], Bs, WC * 64 + nn * 16 + rsub);
    }
    __builtin_amdgcn_s_setprio(1);
#pragma unroll
    for (int mm = 0; mm < 4; mm++) {
      i32x8 aa;
      RD_FRAG(aa, As, WR * 64 + mm * 16 + rsub);
#pragma unroll
      for (int nn = 0; nn < 4; nn++) {
        acc[mm][nn] = __builtin_amdgcn_mfma_scale_f32_16x16x128_f8f6f4(
            aa, bb[nn], acc[mm][nn], 0, 0, 0, 0x7f7f7f7f, 0, 0x7f7f7f7f);
      }
    }
    __builtin_amdgcn_s_setprio(0);

    __syncthreads();                 // all waves done reading tile kt
    if (kt + 1 < NKT) {
      WRITEP();                      // compiler waits loads, then ds_write_b128
      __syncthreads();               // writes visible to all
    }
  }

  // ---- epilogue: C/D layout col=lane&15, row=(lane>>4)*4+reg ----
  const int hi4 = lane >> 4;
  const int col_l = lane & 15;
  float ssim = 0.f;
#pragma unroll
  for (int m = 0; m < 4; m++) {
    const int gibase = i0 + WR * 64 + m * 16 + hi4 * 4;
#pragma unroll
    for (int r = 0; r < 4; r++) {
      const int gi = gibase + r;
      float dsum = 0.f;
#pragma unroll
      for (int n = 0; n < 4; n++) {
        const int gj = j0 + WC * 64 + n * 16 + col_l;
        const float s = acc[m][n][r] * 2.0f;
        const float e = __expf(s);
        if (gj != gi) dsum += e;               // denom excludes diagonal
        if (gj < NROWS && gi < gj) ssim += s;  // triu(rows[:, :n], k=1)
      }
      dsum += __shfl_xor(dsum, 1);
      dsum += __shfl_xor(dsum, 2);
      dsum += __shfl_xor(dsum, 4);
      dsum += __shfl_xor(dsum, 8);
      if (col_l == 0) atomicAdd(&denom[gi], dsum);
    }
  }
#pragma unroll
  for (int msk = 1; msk < 64; msk <<= 1) ssim += __shfl_xor(ssim, msk);
  if (lane == 0 && j0 < NROWS) atomicAdd(sumsim, ssim);
}

__global__ __launch_bounds__(1024) void finalize(const float* __restrict__ denom,
                                                 const float* __restrict__ sumsim,
                                                 float* __restrict__ out) {
  const int t = threadIdx.x;
  double s = 0.0;
#pragma unroll
  for (int i = t; i < NROWS; i += 1024) {
    s += (double)(NROWS - 1 - i) * log((double)denom[i]);
  }
#pragma unroll
  for (int m = 1; m < 64; m <<= 1) s += __shfl_xor(s, m);
  __shared__ double ws_[16];
  if ((t & 63) == 0) ws_[t >> 6] = s;
  __syncthreads();
  if (t == 0) {
    double tot = 0.0;
#pragma unroll
    for (int i = 0; i < 16; i++) tot += ws_[i];
    const double loss = tot - (double)sumsim[0];
    out[0] = (float)(-2.0 / (double)NROWS * (double)(NROWS - 1) * loss);
  }
}

extern "C" void kernel_launch(void* const* d_in, const int* in_sizes, int n_in,
                              void* d_out, int out_size, void* d_ws, size_t ws_size,
                              hipStream_t stream) {
  const float* emb = (const float*)d_in[0];
  unsigned char* zb = (unsigned char*)d_ws;
  float* denom = (float*)((char*)d_ws + (size_t)BROWS * BDIM);  // 8 MB fp8
  float* sumsim = denom + NROWS;
  float* out = (float*)d_out;

  normalize_kernel<<<BROWS / 4, 256, 0, stream>>>(emb, zb, denom, sumsim);
  gemm_fused<<<(NROWS / BM) * (BROWS / BN), 512, 0, stream>>>(zb, denom, sumsim);
  finalize<<<1, 1024, 0, stream>>>(denom, sumsim, out);
}

// Round 17
// 57.001 us; speedup vs baseline: 3.1110x; 3.1110x over previous
//
#include <hip/hip_runtime.h>
#include <stdint.h>

// ContrastiveLoss: B=8192, D=1024, n=2048, T=0.5
// K1: row-normalize f32 -> fp8 e4m3 into MFMA-native 2KB "units"
//     (unit = (row16, kt); gemm-lane l's lo16 at l*16, hi16 at 1024+l*16)
// K2: 128x256-tile MX-fp8 GEMM, 512 thr (8 waves 2x4, wave=64x64, acc=64),
//     UNIT-format LDS (conflict-free dense reads), linear gload_lds staging,
//     single 48KB buffer, 2 barriers/tile, (512,4); XCD-chunked mapping;
//     epilogue: exp-row-sum (diag excluded) + triu sum
// K3: scalar finalize

#define BDIM 1024
#define BROWS 8192
#define NROWS 2048

#define BM 128
#define BN 256
#define NKT 8              // K-tiles of 128 fp8 bytes

typedef __attribute__((ext_vector_type(4))) int i32x4;
typedef __attribute__((ext_vector_type(8))) int i32x8;
typedef __attribute__((ext_vector_type(4))) float f32x4;

// float -> OCP e4m3fn, RNE, handles subnormals (|x| <= 1 for our data)
static __device__ __forceinline__ unsigned char f2e4m3(float x) {
  uint32_t u = __float_as_uint(x);
  uint32_t s = (u >> 24) & 0x80u;
  uint32_t a = u & 0x7fffffffu;
  if (a == 0) return (unsigned char)s;
  int e = (int)(a >> 23) - 127;
  uint32_t m = a & 0x7fffffu;
  if (e >= -6) {
    uint32_t keep = m >> 20;
    uint32_t rest = m & 0xfffffu;
    keep += (rest > 0x80000u) || (rest == 0x80000u && (keep & 1u));
    uint32_t v = ((uint32_t)(e + 7) << 3) + keep;
    return (unsigned char)(s | v);
  }
  if (e < -10) return (unsigned char)s;
  uint32_t full = 0x800000u | m;
  int sh = 14 - e;
  uint32_t keep = full >> sh;
  uint32_t rest = full & ((1u << sh) - 1u);
  uint32_t half = 1u << (sh - 1);
  keep += (rest > half) || (rest == half && (keep & 1u));
  return (unsigned char)(s | keep);
}

static __device__ __forceinline__ void gload_lds16(const unsigned char* g, unsigned char* l) {
  __builtin_amdgcn_global_load_lds(
      (const __attribute__((address_space(1))) uint32_t*)(const void*)g,
      (__attribute__((address_space(3))) uint32_t*)(void*)l,
      16, 0, 0);
}

static __device__ __forceinline__ uint32_t pk4(float4 v, float inv) {
  return (uint32_t)f2e4m3(v.x * inv) | ((uint32_t)f2e4m3(v.y * inv) << 8) |
         ((uint32_t)f2e4m3(v.z * inv) << 16) | ((uint32_t)f2e4m3(v.w * inv) << 24);
}

__global__ __launch_bounds__(256) void normalize_kernel(const float* __restrict__ emb,
                                                        unsigned char* __restrict__ zb,
                                                        float* __restrict__ denom,
                                                        float* __restrict__ sumsim) {
  const int w = threadIdx.x >> 6;
  const int lane = threadIdx.x & 63;
  const int row = blockIdx.x * 4 + w;
  const float4* src = reinterpret_cast<const float4*>(emb + (size_t)row * BDIM);
  float4 v[4];
  float ss = 0.f;
#pragma unroll
  for (int i = 0; i < 4; i++) {
    v[i] = src[lane * 4 + i];
    ss += v[i].x * v[i].x + v[i].y * v[i].y + v[i].z * v[i].z + v[i].w * v[i].w;
  }
#pragma unroll
  for (int m = 1; m < 64; m <<= 1) ss += __shfl_xor(ss, m);
  const float inv = rsqrtf(ss);
  uint4 o;
  o.x = pk4(v[0], inv);
  o.y = pk4(v[1], inv);
  o.z = pk4(v[2], inv);
  o.w = pk4(v[3], inv);
  // unit layout: unit = (row>>4)*8 + (lane>>3); within unit:
  //   half = lane&1, gl = ((lane>>1)&3)*16 + (row&15); off = half*1024 + gl*16
  const size_t unit = (size_t)(row >> 4) * 8 + (lane >> 3);
  const int off = (lane & 1) * 1024 + ((((lane >> 1) & 3) * 16 + (row & 15)) * 16);
  *reinterpret_cast<uint4*>(zb + unit * 2048 + off) = o;
  if (blockIdx.x < NROWS / 4 && lane == 0) denom[row] = 0.f;
  if (blockIdx.x == 0 && threadIdx.x == 0) sumsim[0] = 0.f;
}

// ---------------- GEMM: unit-format LDS, 2-barrier loop ----------------
// LDS: A = 8 units (128 rows), B = 16 units (256 rows) per K-tile = 48 KB.
// Staging (per wave, 6 gloads of 1KB): A unit w; B units 2w, 2w+1.
// Reads: dense lane*16 within unit -> conflict-free (R9/R11-proven).

__global__ __launch_bounds__(512, 4) void gemm_fused(const unsigned char* __restrict__ zb,
                                                     float* __restrict__ denom,
                                                     float* __restrict__ sumsim) {
  __shared__ unsigned char As[8 * 2048];    // 16 KB
  __shared__ unsigned char Bs[16 * 2048];   // 32 KB

  // XCD-chunked: xcd owns 4 j-blocks x all 16 i-blocks (A 2MB + B 1MB < 4MB L2)
  const int bx = blockIdx.x;            // 0..511
  const int xcd = bx & 7;
  const int idx = bx >> 3;              // 0..63
  const int jb = xcd * 4 + (idx & 3);   // 0..31
  const int ib = idx >> 2;              // 0..15
  const int i0 = ib * BM;               // [0,2048)
  const int j0 = jb * BN;               // [0,8192)
  const int i16 = i0 >> 4;
  const int j16 = j0 >> 4;

  const int t = threadIdx.x;
  const int lane = t & 63;
  const int w = t >> 6;                 // 0..7
  const int WR = w >> 2;                // 0..1
  const int WC = w & 3;                 // 0..3

  f32x4 acc[4][4] = {};

#define RDU(dst, base, u)                                                   \
  {                                                                         \
    const unsigned char* p_ = (base) + (u) * 2048 + lane * 16;              \
    const i32x4 lo_ = *reinterpret_cast<const i32x4*>(p_);                  \
    const i32x4 hi_ = *reinterpret_cast<const i32x4*>(p_ + 1024);           \
    dst[0] = lo_[0]; dst[1] = lo_[1]; dst[2] = lo_[2]; dst[3] = lo_[3];     \
    dst[4] = hi_[0]; dst[5] = hi_[1]; dst[6] = hi_[2]; dst[7] = hi_[3];     \
  }

#pragma unroll 1
  for (int kt = 0; kt < NKT; ++kt) {
    // ---- stage tile kt (unit-format, linear source) ----
    {
      const unsigned char* sa = zb + (((size_t)(i16 + w)) * 8 + kt) * 2048 + lane * 16;
      unsigned char* da = As + w * 2048;
      gload_lds16(sa, da);
      gload_lds16(sa + 1024, da + 1024);
#pragma unroll
      for (int uu = 0; uu < 2; ++uu) {
        const int u = 2 * w + uu;
        const unsigned char* sb = zb + (((size_t)(j16 + u)) * 8 + kt) * 2048 + lane * 16;
        unsigned char* db = Bs + u * 2048;
        gload_lds16(sb, db);
        gload_lds16(sb + 1024, db + 1024);
      }
    }
    __syncthreads();  // stage drained (vmcnt0 before barrier)

    i32x8 bb[4];
#pragma unroll
    for (int nn = 0; nn < 4; nn++) {
      RDU(bb[nn], Bs, WC * 4 + nn);
    }
    __builtin_amdgcn_s_setprio(1);
#pragma unroll
    for (int mm = 0; mm < 4; mm++) {
      i32x8 aa;
      RDU(aa, As, WR * 4 + mm);
#pragma unroll
      for (int nn = 0; nn < 4; nn++) {
        acc[mm][nn] = __builtin_amdgcn_mfma_scale_f32_16x16x128_f8f6f4(
            aa, bb[nn], acc[mm][nn], 0, 0, 0, 0x7f7f7f7f, 0, 0x7f7f7f7f);
      }
    }
    __builtin_amdgcn_s_setprio(0);
    __syncthreads();  // reads done before next stage overwrites
  }

  // ---- epilogue: C/D layout col=lane&15, row=(lane>>4)*4+reg ----
  const int hi4 = lane >> 4;
  const int col_l = lane & 15;
  float ssim = 0.f;
#pragma unroll
  for (int m = 0; m < 4; m++) {
    const int gibase = i0 + WR * 64 + m * 16 + hi4 * 4;
#pragma unroll
    for (int r = 0; r < 4; r++) {
      const int gi = gibase + r;
      float dsum = 0.f;
#pragma unroll
      for (int n = 0; n < 4; n++) {
        const int gj = j0 + WC * 64 + n * 16 + col_l;
        const float s = acc[m][n][r] * 2.0f;
        const float e = __expf(s);
        if (gj != gi) dsum += e;               // denom excludes diagonal
        if (gj < NROWS && gi < gj) ssim += s;  // triu(rows[:, :n], k=1)
      }
      dsum += __shfl_xor(dsum, 1);
      dsum += __shfl_xor(dsum, 2);
      dsum += __shfl_xor(dsum, 4);
      dsum += __shfl_xor(dsum, 8);
      if (col_l == 0) atomicAdd(&denom[gi], dsum);
    }
  }
#pragma unroll
  for (int msk = 1; msk < 64; msk <<= 1) ssim += __shfl_xor(ssim, msk);
  if (lane == 0 && j0 < NROWS) atomicAdd(sumsim, ssim);
}

__global__ __launch_bounds__(1024) void finalize(const float* __restrict__ denom,
                                                 const float* __restrict__ sumsim,
                                                 float* __restrict__ out) {
  const int t = threadIdx.x;
  double s = 0.0;
#pragma unroll
  for (int i = t; i < NROWS; i += 1024) {
    s += (double)(NROWS - 1 - i) * log((double)denom[i]);
  }
#pragma unroll
  for (int m = 1; m < 64; m <<= 1) s += __shfl_xor(s, m);
  __shared__ double ws_[16];
  if ((t & 63) == 0) ws_[t >> 6] = s;
  __syncthreads();
  if (t == 0) {
    double tot = 0.0;
#pragma unroll
    for (int i = 0; i < 16; i++) tot += ws_[i];
    const double loss = tot - (double)sumsim[0];
    out[0] = (float)(-2.0 / (double)NROWS * (double)(NROWS - 1) * loss);
  }
}

extern "C" void kernel_launch(void* const* d_in, const int* in_sizes, int n_in,
                              void* d_out, int out_size, void* d_ws, size_t ws_size,
                              hipStream_t stream) {
  const float* emb = (const float*)d_in[0];
  unsigned char* zb = (unsigned char*)d_ws;
  float* denom = (float*)((char*)d_ws + (size_t)BROWS * BDIM);  // 8 MB fp8
  float* sumsim = denom + NROWS;
  float* out = (float*)d_out;

  normalize_kernel<<<BROWS / 4, 256, 0, stream>>>(emb, zb, denom, sumsim);
  gemm_fused<<<(NROWS / BM) * (BROWS / BN), 512, 0, stream>>>(zb, denom, sumsim);
  finalize<<<1, 1024, 0, stream>>>(denom, sumsim, out);
}